// Round 9
// baseline (197.400 us; speedup 1.0000x reference)
//
#include <hip/hip_runtime.h>
#include <hip/hip_bf16.h>

#define HH 256   // hidden dim
#define HJ 128   // H/2
#define GG 512   // number of graphs

typedef __attribute__((ext_vector_type(8))) short short8;
typedef __attribute__((ext_vector_type(4))) float f32x4;

static __device__ __forceinline__ unsigned f2bfu(float f) {
  // round-to-nearest-even fp32 -> bf16 (inputs finite), as low 16 bits
  unsigned u = __builtin_bit_cast(unsigned, f);
  return (u + 0x7FFFu + ((u >> 16) & 1u)) >> 16;
}

// ---------------- Kernel 0: pre-fragment W1^T into MFMA A-operand order ----
// w1a[kt*8+jt][lane] = 8 bf16: A[m=j][k] with j = jt*16+(l&15), k = kt*32+(l>>4)*8+i
__global__ __launch_bounds__(64) void w1frag_kernel(
    const float* __restrict__ W1, short8* __restrict__ w1a) {
  const int l = threadIdx.x;
  const int kt = blockIdx.x >> 3;
  const int jt = blockIdx.x & 7;
  const int j = jt * 16 + (l & 15);
  const int kb = kt * 32 + (l >> 4) * 8;
  short8 v;
#pragma unroll
  for (int i = 0; i < 8; ++i) v[i] = (short)f2bfu(W1[(size_t)(kb + i) * HJ + j]);
  w1a[blockIdx.x * 64 + l] = v;
}

// ---------------- segment offsets from sorted batch ----------------
__global__ __launch_bounds__(256) void segstart_kernel(
    const int* __restrict__ batch, int* __restrict__ segstart, int N, int G) {
  const int n = blockIdx.x * 256 + threadIdx.x;
  if (n >= N) return;
  const int b = batch[n];
  const int p = (n == 0) ? -1 : batch[n - 1];
  for (int g = p + 1; g <= b; ++g) segstart[g] = n;
  if (n == N - 1) {
    for (int g = b + 1; g <= G; ++g) segstart[g] = N;
  }
}

// ---------------- Fused kernel: one block per graph ------------------------
// Wave w owns j-tile jt=w (A-frags in registers). x rows load coalesced in
// two channel-halves (rrA: ch 0..127, rrB: ch 128..255) -> swizzled bf16 LDS
// tile serving both MFMA B-frags and the channel-major pool sweep.
__global__ __launch_bounds__(512, 4) void fused_kernel(
    const float* __restrict__ x, const short8* __restrict__ w1a,
    const float* __restrict__ b1, const float* __restrict__ W2,
    const int* __restrict__ segstart, const float* __restrict__ Wp,
    const float* __restrict__ bp, float4* __restrict__ out4, int N) {
  __shared__ short8 xlds8[4096];    // 64 KB bf16 x-tile [128][256], swizzled
  __shared__ float spart[8 * 128];  // 4 KB; reused as qredf post-loop
  __shared__ float elds[128];
  __shared__ float esl[128];

  const int tid = threadIdx.x;
  const int l = tid & 63;
  const int w = tid >> 6;  // wave 0..7 = j-tile
  const int g = blockIdx.x;

  const int n0 = segstart[g];
  const int n1 = segstart[g + 1];
  const int cnt = n1 - n0;
  if (cnt <= 0) return;  // block-uniform, before any barrier

  const int ntiles = (cnt + 127) >> 7;

  // A-fragments for this wave's j-tile (jt = w): once per block, registers
  short8 afrag[8];
#pragma unroll
  for (int kt = 0; kt < 8; ++kt) afrag[kt] = w1a[(kt * 8 + w) * 64 + l];

  // per-lane b1/W2 for j = 16*w + (l>>4)*4 + r
  const int j0 = 16 * w + (l >> 4) * 4;
  const float4 bb = *reinterpret_cast<const float4*>(b1 + j0);
  const float4 ww = *reinterpret_cast<const float4*>(W2 + j0);

  const int colb = (l & 31) * 16;  // byte offset within a row half
  const int rhalf = l >> 5;        // 0/1: which row of the pair
  float4 rrA[8], rrB[8];           // tile rows: channel-halves 0 / 1

  auto LOADA = [&](int t) {
#pragma unroll
    for (int i = 0; i < 8; ++i) {
      const int node = n0 + t * 128 + w * 16 + 2 * i + rhalf;
      rrA[i] = (node < n1)
                   ? *reinterpret_cast<const float4*>(
                         (const char*)x + (size_t)node * 1024 + colb)
                   : make_float4(0.f, 0.f, 0.f, 0.f);
    }
  };
  auto LOADB = [&](int t) {
#pragma unroll
    for (int i = 0; i < 8; ++i) {
      const int node = n0 + t * 128 + w * 16 + 2 * i + rhalf;
      rrB[i] = (node < n1)
                   ? *reinterpret_cast<const float4*>(
                         (const char*)x + (size_t)node * 1024 + 512 + colb)
                   : make_float4(0.f, 0.f, 0.f, 0.f);
    }
  };
  LOADA(0);
  LOADB(0);

  // sweep mapping: channel pair + node quarter
  const int c2 = tid & 127;
  const int qh = tid >> 7;
  float2 pacc = make_float2(0.f, 0.f);
  float es_acc = 0.f;  // valid for tid<128

  char* xl = (char*)xlds8;

  for (int t = 0; t < ntiles; ++t) {
    // write x-tile t (bf16, XOR-swizzled by node: byte(c) = r*512 + (2c ^ swz))
#pragma unroll
    for (int i = 0; i < 8; ++i) {
      const int r = w * 16 + 2 * i + rhalf;
      const int swz = (r & 7) << 4;
      const unsigned loA = f2bfu(rrA[i].x) | (f2bfu(rrA[i].y) << 16);
      const unsigned hiA = f2bfu(rrA[i].z) | (f2bfu(rrA[i].w) << 16);
      *reinterpret_cast<uint2*>(xl + r * 512 + ((((l & 31) * 8)) ^ swz)) =
          make_uint2(loA, hiA);
      const unsigned loB = f2bfu(rrB[i].x) | (f2bfu(rrB[i].y) << 16);
      const unsigned hiB = f2bfu(rrB[i].z) | (f2bfu(rrB[i].w) << 16);
      *reinterpret_cast<uint2*>(xl + r * 512 + ((256 + ((l & 31) * 8)) ^ swz)) =
          make_uint2(loB, hiB);
    }
    __syncthreads();  // x-tile t visible

    // prefetch next tile's first channel-half (hides under MFMA phase)
    if (t + 1 < ntiles) LOADA(t + 1);

    // gate GEMM + epilogue, nt-outer (2 ping-pong accs to cut reg pressure)
#pragma unroll
    for (int nt = 0; nt < 8; ++nt) {
      const int node = nt * 16 + (l & 15);
      const int nb = node * 512;
      const int swz = (node & 7) << 4;
      f32x4 a0 = (f32x4)(0.f), a1 = (f32x4)(0.f);
#pragma unroll
      for (int kt = 0; kt < 8; kt += 2) {
        const short8 bf0 = *reinterpret_cast<const short8*>(
            xl + nb + ((kt * 64 + ((l >> 4) << 4)) ^ swz));
        const short8 bf1 = *reinterpret_cast<const short8*>(
            xl + nb + (((kt + 1) * 64 + ((l >> 4) << 4)) ^ swz));
        a0 = __builtin_amdgcn_mfma_f32_16x16x32_bf16(afrag[kt], bf0, a0, 0, 0, 0);
        a1 = __builtin_amdgcn_mfma_f32_16x16x32_bf16(afrag[kt + 1], bf1, a1, 0, 0, 0);
      }
      const f32x4 acc = a0 + a1;
      // partial s over this wave's 16 j's, per node
      float t0 = __expf(2.f * (acc[0] + bb.x));
      float t1 = __expf(2.f * (acc[1] + bb.y));
      float t2 = __expf(2.f * (acc[2] + bb.z));
      float t3 = __expf(2.f * (acc[3] + bb.w));
      float ps = (1.f - 2.f / (t0 + 1.f)) * ww.x +
                 (1.f - 2.f / (t1 + 1.f)) * ww.y +
                 (1.f - 2.f / (t2 + 1.f)) * ww.z +
                 (1.f - 2.f / (t3 + 1.f)) * ww.w;
      ps += __shfl_xor(ps, 16, 64);
      ps += __shfl_xor(ps, 32, 64);
      if (l < 16) spart[w * 128 + nt * 16 + l] = ps;
    }
    __syncthreads();  // spart ready

    // combine j-slices -> s -> e (one thread per node)
    if (tid < 128) {
      float s = 0.f;
#pragma unroll
      for (int wv = 0; wv < 8; ++wv) s += spart[wv * 128 + tid];
      const int node = n0 + t * 128 + tid;
      const float e = (node < n1) ? __expf(s) : 0.f;
      elds[tid] = e;
      es_acc += e;
    }
    __syncthreads();  // elds ready

    // prefetch next tile's second channel-half (hides under sweep)
    if (t + 1 < ntiles) LOADB(t + 1);

    // channel-major pool sweep: thread (c2,qh): channels {2c2,2c2+1},
    // nodes [qh*32, qh*32+32). Invalid nodes have e=0.
#pragma unroll 8
    for (int m = 0; m < 32; ++m) {
      const int n = qh * 32 + m;
      const unsigned v = *reinterpret_cast<const unsigned*>(
          xl + n * 512 + ((c2 * 4) ^ ((n & 7) << 4)));
      const float ee = elds[n];
      const float xlo = __builtin_bit_cast(float, v << 16);
      const float xhi = __builtin_bit_cast(float, v & 0xFFFF0000u);
      pacc.x = fmaf(xlo, ee, pacc.x);
      pacc.y = fmaf(xhi, ee, pacc.y);
    }
    __syncthreads();  // sweep done; next iter may overwrite x-tile
  }

  // ---- combine quarter partials; spart reused as qredf [4][256] ----
  float* qredf = spart;
  qredf[qh * 256 + c2 * 2] = pacc.x;
  qredf[qh * 256 + c2 * 2 + 1] = pacc.y;
  if (tid < 128) esl[tid] = es_acc;
  __syncthreads();
  if (tid < 64) esl[tid] += esl[tid + 64];
  __syncthreads();

  float* er = (float*)xlds8;  // x-tile dead: reuse for emb/proj buffers
  if (tid < HH) {
    float es = 0.f;
#pragma unroll 8
    for (int i = 0; i < 64; ++i) es += esl[i];
    const float inv = (es > 0.f) ? 1.f / es : 0.f;
    const float emb =
        qredf[tid] + qredf[256 + tid] + qredf[512 + tid] + qredf[768 + tid];
    er[tid] = emb * inv;
  }
  __syncthreads();

  // projection: ctx = er @ Wp + bp, split over k-halves
  float* pr = er + 256;  // [2][256]
  {
    const int c = tid & 255;
    const int h = tid >> 8;
    float p = 0.f;
    const float* wp = Wp + (size_t)h * 128 * HH + c;
#pragma unroll 4
    for (int k = 0; k < 128; ++k) {
      p = fmaf(er[h * 128 + k], wp[(size_t)k * HH], p);
    }
    pr[h * 256 + c] = p;
  }
  __syncthreads();
  float* ctxl = pr + 512;
  if (tid < HH) {
    ctxl[tid] = pr[tid] + pr[256 + tid] + bp[tid];
  }
  __syncthreads();

  // broadcast ctx row to all nodes of the graph (coalesced 1KB/wave rows)
  {
    const int q = tid & 63;
    const float4 cv = reinterpret_cast<const float4*>(ctxl)[q];
    for (int n = n0 + w; n < n1; n += 8) {
      out4[(size_t)n * 64 + q] = cv;
    }
  }
}

extern "C" void kernel_launch(void* const* d_in, const int* in_sizes, int n_in,
                              void* d_out, int out_size, void* d_ws, size_t ws_size,
                              hipStream_t stream) {
  const float* x = (const float*)d_in[0];
  const int* batch = (const int*)d_in[1];
  const float* W1 = (const float*)d_in[2];
  const float* b1 = (const float*)d_in[3];
  const float* W2 = (const float*)d_in[4];
  // d_in[5] = b2 (unused: softmax shift-invariant)
  const float* Wp = (const float*)d_in[6];
  const float* bp = (const float*)d_in[7];
  float* out = (float*)d_out;

  const int N = in_sizes[1];
  const int G = GG;

  // workspace layout (16B aligned)
  char* wsp = (char*)d_ws;
  short8* w1a = (short8*)wsp;           // 4096 short8 = 64 KB
  size_t off = 4096 * sizeof(short8);
  int* segstart = (int*)(wsp + off);    // G+1 ints

  // fragment W1
  w1frag_kernel<<<dim3(64), 64, 0, stream>>>(W1, w1a);
  // segment offsets
  {
    dim3 grid((N + 255) / 256);
    segstart_kernel<<<grid, 256, 0, stream>>>(batch, segstart, N, G);
  }
  // fused gate + pool + project + broadcast
  fused_kernel<<<dim3(G), 512, 0, stream>>>(x, w1a, b1, W2, segstart, Wp, bp,
                                            (float4*)out, N);
}